// Round 1
// baseline (637.869 us; speedup 1.0000x reference)
//
#include <hip/hip_runtime.h>

#define IN_CH 128
#define OUT_CH 64

// ---------------- deg[j] += ew[e] for e with col[e]==j ----------------
__global__ __launch_bounds__(256) void k_deg(const int* __restrict__ col,
                                             const float* __restrict__ ew,
                                             float* __restrict__ deg, int E) {
    int e = blockIdx.x * 256 + threadIdx.x;
    if (e < E) unsafeAtomicAdd(&deg[col[e]], ew[e]);
}

// ---------------- dis[i] = deg>0 ? rsqrt(deg) : 0 ----------------
__global__ __launch_bounds__(256) void k_dis(const float* __restrict__ deg,
                                             float* __restrict__ dis, int N) {
    int i = blockIdx.x * 256 + threadIdx.x;
    if (i < N) {
        float d = deg[i];
        dis[i] = (d > 0.f) ? rsqrtf(d) : 0.f;
    }
}

// ---------------- h = x @ W  (N x 128) @ (128 x 64) ----------------
// Block: 256 threads = 4 waves. Wave handles one row at a time, lane = out col.
// W staged in LDS (128*64*4B = 32 KB). x row loads are wave-uniform (broadcast).
__global__ __launch_bounds__(256) void k_gemm(const float* __restrict__ x,
                                              const float* __restrict__ W,
                                              float* __restrict__ h, int N) {
    __shared__ float sW[IN_CH * OUT_CH];
    for (int i = threadIdx.x; i < IN_CH * OUT_CH; i += 256) sW[i] = W[i];
    __syncthreads();

    const int ROWS = 16;
    int row0 = blockIdx.x * ROWS;
    int lane_col = threadIdx.x & 63;  // out channel
    int rg = threadIdx.x >> 6;        // wave id in block (0..3)

    for (int r = rg; r < ROWS; r += 4) {
        int row = row0 + r;
        if (row >= N) break;
        const float4* xr = (const float4*)(x + (size_t)row * IN_CH);
        float acc = 0.f;
#pragma unroll
        for (int k4 = 0; k4 < IN_CH / 4; ++k4) {
            float4 xv = xr[k4];
            acc += xv.x * sW[(k4 * 4 + 0) * OUT_CH + lane_col];
            acc += xv.y * sW[(k4 * 4 + 1) * OUT_CH + lane_col];
            acc += xv.z * sW[(k4 * 4 + 2) * OUT_CH + lane_col];
            acc += xv.w * sW[(k4 * 4 + 3) * OUT_CH + lane_col];
        }
        h[(size_t)row * OUT_CH + lane_col] = acc;
    }
}

// ---------------- out[col[e]] += norm[e] * h[row[e]]  ----------------
// One wave per edge per iteration; lane = out channel. Grid-stride over edges.
__global__ __launch_bounds__(256) void k_agg(const int* __restrict__ row,
                                             const int* __restrict__ col,
                                             const float* __restrict__ ew,
                                             const float* __restrict__ dis,
                                             const float* __restrict__ h,
                                             float* __restrict__ out, int E) {
    int wave = (blockIdx.x * 256 + threadIdx.x) >> 6;
    int lane = threadIdx.x & 63;
    int nwaves = (gridDim.x * 256) >> 6;
    for (int e = wave; e < E; e += nwaves) {
        int r = row[e];
        int c = col[e];
        float nrm = dis[r] * ew[e] * dis[c];
        float v = nrm * h[(size_t)r * OUT_CH + lane];
        unsafeAtomicAdd(&out[(size_t)c * OUT_CH + lane], v);
    }
}

// ---------------- out = sigmoid(out + b) ----------------
__global__ __launch_bounds__(256) void k_final(float* __restrict__ out,
                                               const float* __restrict__ b,
                                               int total4) {
    int i = blockIdx.x * 256 + threadIdx.x;
    if (i < total4) {
        float4 v = ((float4*)out)[i];
        int c = (i * 4) & (OUT_CH - 1);
        v.x = 1.f / (1.f + __expf(-(v.x + b[c + 0])));
        v.y = 1.f / (1.f + __expf(-(v.y + b[c + 1])));
        v.z = 1.f / (1.f + __expf(-(v.z + b[c + 2])));
        v.w = 1.f / (1.f + __expf(-(v.w + b[c + 3])));
        ((float4*)out)[i] = v;
    }
}

extern "C" void kernel_launch(void* const* d_in, const int* in_sizes, int n_in,
                              void* d_out, int out_size, void* d_ws, size_t ws_size,
                              hipStream_t stream) {
    const float* x   = (const float*)d_in[0];
    const int*   ei  = (const int*)d_in[1];    // [2, E] flat
    const float* ew  = (const float*)d_in[2];
    const float* W   = (const float*)d_in[3];
    const float* b   = (const float*)d_in[4];
    float* out = (float*)d_out;

    const int N = in_sizes[0] / IN_CH;
    const int E = in_sizes[1] / 2;
    const int* row = ei;       // edge_index[0]
    const int* col = ei + E;   // edge_index[1]

    // workspace: deg[N] | dis[N] | h[N*OUT_CH]
    float* deg = (float*)d_ws;
    float* dis = deg + N;
    float* h   = dis + N;

    hipMemsetAsync(deg, 0, (size_t)N * sizeof(float), stream);
    hipMemsetAsync(d_out, 0, (size_t)out_size * sizeof(float), stream);

    k_deg<<<(E + 255) / 256, 256, 0, stream>>>(col, ew, deg, E);
    k_dis<<<(N + 255) / 256, 256, 0, stream>>>(deg, dis, N);
    k_gemm<<<(N + 15) / 16, 256, 0, stream>>>(x, W, h, N);
    k_agg<<<16384, 256, 0, stream>>>(row, col, ew, dis, h, out, E);

    int total4 = (N * OUT_CH) / 4;
    k_final<<<(total4 + 255) / 256, 256, 0, stream>>>(out, b, total4);
}

// Round 2
// 456.954 us; speedup vs baseline: 1.3959x; 1.3959x over previous
//
#include <hip/hip_runtime.h>

#define IN_CH 128
#define OUT_CH 64
#define CHUNK 512

// ---------------- deg[c] += ew[e]; cnt[c] += 1 ----------------
__global__ __launch_bounds__(256) void k_deg_cnt(const int* __restrict__ col,
                                                 const float* __restrict__ ew,
                                                 float* __restrict__ deg,
                                                 int* __restrict__ cnt, int E) {
    int e = blockIdx.x * 256 + threadIdx.x;
    if (e < E) {
        int c = col[e];
        unsafeAtomicAdd(&deg[c], ew[e]);
        atomicAdd(&cnt[c], 1);
    }
}

// ---------------- dis[i] = deg>0 ? rsqrt(deg) : 0 ----------------
__global__ __launch_bounds__(256) void k_dis(const float* __restrict__ deg,
                                             float* __restrict__ dis, int N) {
    int i = blockIdx.x * 256 + threadIdx.x;
    if (i < N) {
        float d = deg[i];
        dis[i] = (d > 0.f) ? rsqrtf(d) : 0.f;
    }
}

// ---------------- scan stage 1: per-chunk inclusive scan ----------------
__global__ __launch_bounds__(CHUNK) void k_scan1(const int* __restrict__ cnt,
                                                 int* __restrict__ incl,
                                                 int* __restrict__ partial, int N) {
    __shared__ int s[CHUNK];
    int i = blockIdx.x * CHUNK + threadIdx.x;
    s[threadIdx.x] = (i < N) ? cnt[i] : 0;
    __syncthreads();
    for (int off = 1; off < CHUNK; off <<= 1) {
        int t = (threadIdx.x >= off) ? s[threadIdx.x - off] : 0;
        __syncthreads();
        s[threadIdx.x] += t;
        __syncthreads();
    }
    if (i < N) incl[i] = s[threadIdx.x];
    if (threadIdx.x == CHUNK - 1) partial[blockIdx.x] = s[CHUNK - 1];
}

// ---------------- scan stage 2: scan of chunk totals (NB <= 256) ----------------
__global__ __launch_bounds__(256) void k_scan2(int* __restrict__ partial, int NB) {
    __shared__ int s[256];
    s[threadIdx.x] = (threadIdx.x < NB) ? partial[threadIdx.x] : 0;
    __syncthreads();
    for (int off = 1; off < 256; off <<= 1) {
        int t = (threadIdx.x >= off) ? s[threadIdx.x - off] : 0;
        __syncthreads();
        s[threadIdx.x] += t;
        __syncthreads();
    }
    int excl = (threadIdx.x == 0) ? 0 : s[threadIdx.x - 1];
    if (threadIdx.x < NB) partial[threadIdx.x] = excl;
}

// ---------------- scan stage 3: start = incl - cnt + chunk_off; cursor = start ----------------
__global__ __launch_bounds__(256) void k_scan3(const int* __restrict__ cnt,
                                               int* __restrict__ start,   // holds incl on entry
                                               int* __restrict__ cursor,
                                               const int* __restrict__ partial, int N) {
    int i = blockIdx.x * 256 + threadIdx.x;
    if (i < N) {
        int st = start[i] - cnt[i] + partial[i / CHUNK];
        start[i] = st;
        cursor[i] = st;
    }
}

// ---------------- scatter: pairs[p] = (src, norm) sorted by dst ----------------
__global__ __launch_bounds__(256) void k_scatter(const int* __restrict__ row,
                                                 const int* __restrict__ col,
                                                 const float* __restrict__ ew,
                                                 const float* __restrict__ dis,
                                                 int* __restrict__ cursor,
                                                 float2* __restrict__ pairs, int E) {
    int e = blockIdx.x * 256 + threadIdx.x;
    if (e < E) {
        int r = row[e];
        int c = col[e];
        int p = atomicAdd(&cursor[c], 1);
        float nrm = dis[r] * ew[e] * dis[c];
        pairs[p] = make_float2(__int_as_float(r), nrm);
    }
}

// ---------------- h = x @ W : 64x64 tile, thread = 4 rows x 4 cols ----------------
__global__ __launch_bounds__(256) void k_gemm2(const float* __restrict__ x,
                                               const float* __restrict__ W,
                                               float* __restrict__ h, int N) {
    __shared__ float xs[64][17];   // +1 pad: conflict-free column reads
    __shared__ float Ws[16][64];
    int tc = threadIdx.x & 15;   // col group: cols 4*tc..+3
    int tr = threadIdx.x >> 4;   // row group: rows 4*tr..+3
    int row0 = blockIdx.x * 64;

    float acc[4][4] = {};

    for (int k0 = 0; k0 < IN_CH; k0 += 16) {
        // stage x tile: 64 rows x 16 k
        {
            int r = threadIdx.x >> 2;
            int cc = (threadIdx.x & 3) * 4;
            int gr = row0 + r;
            float4 v = make_float4(0.f, 0.f, 0.f, 0.f);
            if (gr < N) v = *(const float4*)(x + (size_t)gr * IN_CH + k0 + cc);
            xs[r][cc + 0] = v.x; xs[r][cc + 1] = v.y;
            xs[r][cc + 2] = v.z; xs[r][cc + 3] = v.w;
        }
        // stage W tile: 16 k x 64 cols
        {
            int r = threadIdx.x >> 4;
            int cc = (threadIdx.x & 15) * 4;
            *(float4*)&Ws[r][cc] = *(const float4*)(W + (size_t)(k0 + r) * OUT_CH + cc);
        }
        __syncthreads();
#pragma unroll
        for (int kk = 0; kk < 16; ++kk) {
            float a0 = xs[4 * tr + 0][kk];
            float a1 = xs[4 * tr + 1][kk];
            float a2 = xs[4 * tr + 2][kk];
            float a3 = xs[4 * tr + 3][kk];
            float4 bv = *(const float4*)&Ws[kk][4 * tc];
            acc[0][0] += a0 * bv.x; acc[0][1] += a0 * bv.y; acc[0][2] += a0 * bv.z; acc[0][3] += a0 * bv.w;
            acc[1][0] += a1 * bv.x; acc[1][1] += a1 * bv.y; acc[1][2] += a1 * bv.z; acc[1][3] += a1 * bv.w;
            acc[2][0] += a2 * bv.x; acc[2][1] += a2 * bv.y; acc[2][2] += a2 * bv.z; acc[2][3] += a2 * bv.w;
            acc[3][0] += a3 * bv.x; acc[3][1] += a3 * bv.y; acc[3][2] += a3 * bv.z; acc[3][3] += a3 * bv.w;
        }
        __syncthreads();
    }
#pragma unroll
    for (int i = 0; i < 4; ++i) {
        int gr = row0 + 4 * tr + i;
        if (gr < N) {
            float4 v = make_float4(acc[i][0], acc[i][1], acc[i][2], acc[i][3]);
            *(float4*)(h + (size_t)gr * OUT_CH + 4 * tc) = v;
        }
    }
}

// ---------------- agg: wave per dst node, fused bias+sigmoid ----------------
__global__ __launch_bounds__(256) void k_agg2(const float2* __restrict__ pairs,
                                              const int* __restrict__ start,
                                              const int* __restrict__ cnt,
                                              const float* __restrict__ h,
                                              const float* __restrict__ b,
                                              float* __restrict__ out, int N) {
    int c = (blockIdx.x * 256 + threadIdx.x) >> 6;
    int lane = threadIdx.x & 63;
    if (c >= N) return;
    int s = start[c];
    int n = cnt[c];
    float acc = 0.f;
    int e = s;
    int end = s + n;
    for (; e + 1 < end; e += 2) {
        float2 p0 = pairs[e];
        float2 p1 = pairs[e + 1];
        acc += p0.y * h[(size_t)__float_as_int(p0.x) * OUT_CH + lane];
        acc += p1.y * h[(size_t)__float_as_int(p1.x) * OUT_CH + lane];
    }
    if (e < end) {
        float2 p = pairs[e];
        acc += p.y * h[(size_t)__float_as_int(p.x) * OUT_CH + lane];
    }
    out[(size_t)c * OUT_CH + lane] = 1.f / (1.f + __expf(-(acc + b[lane])));
}

extern "C" void kernel_launch(void* const* d_in, const int* in_sizes, int n_in,
                              void* d_out, int out_size, void* d_ws, size_t ws_size,
                              hipStream_t stream) {
    const float* x   = (const float*)d_in[0];
    const int*   ei  = (const int*)d_in[1];
    const float* ew  = (const float*)d_in[2];
    const float* W   = (const float*)d_in[3];
    const float* b   = (const float*)d_in[4];
    float* out = (float*)d_out;

    const int N = in_sizes[0] / IN_CH;
    const int E = in_sizes[1] / 2;
    const int* row = ei;
    const int* col = ei + E;
    const int NB = (N + CHUNK - 1) / CHUNK;   // 196 for N=100000 (must be <=256)

    // ws layout: deg[N] f32 | cnt[N] i32 | dis[N] f32 | start[N] i32 | cursor[N] i32
    //          | partial[256] i32 | h[N*64] f32 | pairs[E] float2
    char* p = (char*)d_ws;
    float* deg    = (float*)p;            p += (size_t)N * 4;
    int*   cnt    = (int*)p;              p += (size_t)N * 4;
    float* dis    = (float*)p;            p += (size_t)N * 4;
    int*   start  = (int*)p;              p += (size_t)N * 4;
    int*   cursor = (int*)p;              p += (size_t)N * 4;
    int*   partial= (int*)p;              p += 1024;
    float* h      = (float*)p;            p += (size_t)N * OUT_CH * 4;
    float2* pairs = (float2*)p;

    // zero deg+cnt (adjacent)
    hipMemsetAsync(deg, 0, (size_t)N * 8, stream);

    k_deg_cnt<<<(E + 255) / 256, 256, 0, stream>>>(col, ew, deg, cnt, E);
    k_dis<<<(N + 255) / 256, 256, 0, stream>>>(deg, dis, N);
    k_scan1<<<NB, CHUNK, 0, stream>>>(cnt, start, partial, N);
    k_scan2<<<1, 256, 0, stream>>>(partial, NB);
    k_scan3<<<(N + 255) / 256, 256, 0, stream>>>(cnt, start, cursor, partial, N);
    k_scatter<<<(E + 255) / 256, 256, 0, stream>>>(row, col, ew, dis, cursor, pairs, E);
    k_gemm2<<<(N + 63) / 64, 256, 0, stream>>>(x, W, h, N);
    k_agg2<<<((size_t)N * 64 + 255) / 256, 256, 0, stream>>>(pairs, start, cnt, h, b, out, N);
}